// Round 1
// baseline (476.413 us; speedup 1.0000x reference)
//
#include <hip/hip_runtime.h>
#include <hip/hip_bf16.h>

#define BB 2
#define SS 2048
#define DD 1024
#define HH 16
#define DKV 64

typedef __attribute__((ext_vector_type(8))) short short8;
typedef __attribute__((ext_vector_type(4))) float f32x4;

#define MFMA16(a, b, c) __builtin_amdgcn_mfma_f32_16x16x32_bf16(a, b, c, 0, 0, 0)

__device__ __forceinline__ short f2bf(float f) {
    __hip_bfloat16 h = __float2bfloat16(f);
    union { __hip_bfloat16 h; short s; } u;
    u.h = h;
    return u.s;
}

// ---------------------------------------------------------------------------
// Projection GEMM: outh[b][h][s][64] (bf16) = A[M=4096,K=1024] @ W[K,N=1024] + bias
// tile 128x128, BK=32, 256 threads = 4 waves (2x2), each wave 64x64 (4x4 frags)
// ---------------------------------------------------------------------------
__global__ __launch_bounds__(256) void proj_kernel(
    const float* __restrict__ A, const float* __restrict__ W,
    const float* __restrict__ bias, __hip_bfloat16* __restrict__ outh)
{
    __shared__ __align__(16) short As[128][40];
    __shared__ __align__(16) short Bs[128][40];  // transposed: Bs[col][k]
    const int t = threadIdx.x;
    const int lane = t & 63;
    const int wave = t >> 6;
    const int wm = wave >> 1, wn = wave & 1;
    const int m0 = blockIdx.x * 128, n0 = blockIdx.y * 128;
    const int lr = lane & 15;
    const int kb = (lane >> 4) * 8;

    f32x4 acc[4][4] = {};

    for (int k0 = 0; k0 < DD; k0 += 32) {
        __syncthreads();  // protect LDS from previous iteration's readers
        // stage A: 128 rows x 32 k; 2 threads/row, 16 floats each
        {
            const int row = t >> 1, kk = (t & 1) * 16;
            const float* src = A + (size_t)(m0 + row) * DD + k0 + kk;
            float4 fa = *(const float4*)(src);
            float4 fb = *(const float4*)(src + 4);
            float4 fc = *(const float4*)(src + 8);
            float4 fd = *(const float4*)(src + 12);
            short8 v0 = { f2bf(fa.x), f2bf(fa.y), f2bf(fa.z), f2bf(fa.w),
                          f2bf(fb.x), f2bf(fb.y), f2bf(fb.z), f2bf(fb.w) };
            short8 v1 = { f2bf(fc.x), f2bf(fc.y), f2bf(fc.z), f2bf(fc.w),
                          f2bf(fd.x), f2bf(fd.y), f2bf(fd.z), f2bf(fd.w) };
            *(short8*)&As[row][kk]     = v0;
            *(short8*)&As[row][kk + 8] = v1;
        }
        // stage B transposed: 32 k-rows x 128 cols; 8 threads/k-row
        {
            const int kk = t >> 3, c0 = (t & 7) * 16;
            const float* src = W + (size_t)(k0 + kk) * DD + n0 + c0;
            #pragma unroll
            for (int i = 0; i < 16; i += 4) {
                float4 f = *(const float4*)(src + i);
                Bs[c0 + i + 0][kk] = f2bf(f.x);
                Bs[c0 + i + 1][kk] = f2bf(f.y);
                Bs[c0 + i + 2][kk] = f2bf(f.z);
                Bs[c0 + i + 3][kk] = f2bf(f.w);
            }
        }
        __syncthreads();
        short8 af[4], bfr[4];
        #pragma unroll
        for (int i = 0; i < 4; i++) af[i]  = *(const short8*)&As[wm * 64 + i * 16 + lr][kb];
        #pragma unroll
        for (int j = 0; j < 4; j++) bfr[j] = *(const short8*)&Bs[wn * 64 + j * 16 + lr][kb];
        #pragma unroll
        for (int i = 0; i < 4; i++)
            #pragma unroll
            for (int j = 0; j < 4; j++)
                acc[i][j] = MFMA16(af[i], bfr[j], acc[i][j]);
    }

    // epilogue: D layout col=lane&15, row=(lane>>4)*4+r
    #pragma unroll
    for (int j = 0; j < 4; j++) {
        const int col = n0 + wn * 64 + j * 16 + lr;
        const float bv = bias[col];
        const int h = col >> 6, d = col & 63;
        #pragma unroll
        for (int i = 0; i < 4; i++) {
            #pragma unroll
            for (int r = 0; r < 4; r++) {
                const int m = m0 + wm * 64 + i * 16 + (lane >> 4) * 4 + r;
                const int b = m >> 11, s = m & (SS - 1);
                outh[(((size_t)(b * HH + h)) * SS + s) * DKV + d] =
                    __float2bfloat16(acc[i][j][r] + bv);
            }
        }
    }
}

// ---------------------------------------------------------------------------
// Output GEMM: out[M,N] (fp32) = ctx[M,K](bf16) @ wo[K,N] + bo + residual
// ---------------------------------------------------------------------------
__global__ __launch_bounds__(256) void outproj_kernel(
    const __hip_bfloat16* __restrict__ Actx, const float* __restrict__ W,
    const float* __restrict__ bias, const float* __restrict__ resid,
    float* __restrict__ out)
{
    __shared__ __align__(16) short As[128][40];
    __shared__ __align__(16) short Bs[128][40];
    const int t = threadIdx.x;
    const int lane = t & 63;
    const int wave = t >> 6;
    const int wm = wave >> 1, wn = wave & 1;
    const int m0 = blockIdx.x * 128, n0 = blockIdx.y * 128;
    const int lr = lane & 15;
    const int kb = (lane >> 4) * 8;

    f32x4 acc[4][4] = {};

    for (int k0 = 0; k0 < DD; k0 += 32) {
        __syncthreads();
        {
            const int row = t >> 1, kk = (t & 1) * 16;
            const short8* src = (const short8*)((const short*)Actx + (size_t)(m0 + row) * DD + k0 + kk);
            *(short8*)&As[row][kk]     = src[0];
            *(short8*)&As[row][kk + 8] = src[1];
        }
        {
            const int kk = t >> 3, c0 = (t & 7) * 16;
            const float* src = W + (size_t)(k0 + kk) * DD + n0 + c0;
            #pragma unroll
            for (int i = 0; i < 16; i += 4) {
                float4 f = *(const float4*)(src + i);
                Bs[c0 + i + 0][kk] = f2bf(f.x);
                Bs[c0 + i + 1][kk] = f2bf(f.y);
                Bs[c0 + i + 2][kk] = f2bf(f.z);
                Bs[c0 + i + 3][kk] = f2bf(f.w);
            }
        }
        __syncthreads();
        short8 af[4], bfr[4];
        #pragma unroll
        for (int i = 0; i < 4; i++) af[i]  = *(const short8*)&As[wm * 64 + i * 16 + lr][kb];
        #pragma unroll
        for (int j = 0; j < 4; j++) bfr[j] = *(const short8*)&Bs[wn * 64 + j * 16 + lr][kb];
        #pragma unroll
        for (int i = 0; i < 4; i++)
            #pragma unroll
            for (int j = 0; j < 4; j++)
                acc[i][j] = MFMA16(af[i], bfr[j], acc[i][j]);
    }

    #pragma unroll
    for (int j = 0; j < 4; j++) {
        const int col = n0 + wn * 64 + j * 16 + lr;
        const float bv = bias[col];
        #pragma unroll
        for (int i = 0; i < 4; i++) {
            #pragma unroll
            for (int r = 0; r < 4; r++) {
                const int m = m0 + wm * 64 + i * 16 + (lane >> 4) * 4 + r;
                out[(size_t)m * DD + col] = acc[i][j][r] + bv + resid[(size_t)m * DD + col];
            }
        }
    }
}

// ---------------------------------------------------------------------------
// Attention: per (b, h, 64-row q-tile). Two-pass max-free softmax.
// Scores bounded (|s| <~ 5) so exp() cannot overflow; masked -> exp(-1e9) = 0.
// ---------------------------------------------------------------------------
__global__ __launch_bounds__(256) void attn_kernel(
    const __hip_bfloat16* __restrict__ qh, const __hip_bfloat16* __restrict__ kh,
    const __hip_bfloat16* __restrict__ vh, const int* __restrict__ mask,
    float* __restrict__ attn, __hip_bfloat16* __restrict__ ctx)
{
    __shared__ __align__(16) short Qs[64][72];
    __shared__ __align__(16) short Ks[64][72];
    __shared__ __align__(16) short VsT[64][72];  // VsT[d][k]
    __shared__ __align__(16) short Ps[64][72];
    const int t = threadIdx.x, lane = t & 63, w = t >> 6;
    const int bid = blockIdx.x;
    const int h = bid & (HH - 1);
    const int bq = bid >> 4;
    const int b = bq >> 5;   // 32 q-tiles of 64
    const int qt = bq & 31;
    const int q0 = qt * 64;
    const size_t headbase = ((size_t)(b * HH + h)) * SS * DKV;
    const int lr = lane & 15, kb = (lane >> 4) * 8;
    const int rbase = (lane >> 4) * 4;

    // load Q tile (stays resident)
    {
        const int row = t >> 2, c = (t & 3) * 16;
        const short8* src = (const short8*)((const short*)qh + headbase + (size_t)(q0 + row) * DKV + c);
        *(short8*)&Qs[row][c]     = src[0];
        *(short8*)&Qs[row][c + 8] = src[1];
    }
    __syncthreads();
    const short8 aq0 = *(const short8*)&Qs[w * 16 + lr][kb];
    const short8 aq1 = *(const short8*)&Qs[w * 16 + lr][32 + kb];

    float lsum[4] = {0.f, 0.f, 0.f, 0.f};

    // ---------------- pass 1: row sums of exp(masked scores) ----------------
    for (int kt = 0; kt < 32; ++kt) {
        const int k0 = kt * 64;
        __syncthreads();
        {
            const int row = t >> 2, c = (t & 3) * 16;
            const short8* src = (const short8*)((const short*)kh + headbase + (size_t)(k0 + row) * DKV + c);
            *(short8*)&Ks[row][c]     = src[0];
            *(short8*)&Ks[row][c + 8] = src[1];
        }
        __syncthreads();
        #pragma unroll
        for (int fc = 0; fc < 4; ++fc) {
            short8 bk0 = *(const short8*)&Ks[fc * 16 + lr][kb];
            short8 bk1 = *(const short8*)&Ks[fc * 16 + lr][32 + kb];
            f32x4 sc = {0.f, 0.f, 0.f, 0.f};
            sc = MFMA16(aq0, bk0, sc);
            sc = MFMA16(aq1, bk1, sc);
            const int kcol = k0 + fc * 16 + lr;
            #pragma unroll
            for (int r = 0; r < 4; ++r) {
                const int qrow = q0 + w * 16 + rbase + r;
                const int mv = mask[((size_t)b * SS + qrow) * SS + kcol];
                float p = mv ? 0.f : __expf(sc[r] * 0.125f);
                lsum[r] += p;
            }
        }
    }
    // reduce across the 16 lanes that share rows
    #pragma unroll
    for (int r = 0; r < 4; r++) {
        float s = lsum[r];
        s += __shfl_xor(s, 1);
        s += __shfl_xor(s, 2);
        s += __shfl_xor(s, 4);
        s += __shfl_xor(s, 8);
        lsum[r] = s;
    }
    float linv[4];
    #pragma unroll
    for (int r = 0; r < 4; r++) linv[r] = 1.f / lsum[r];

    f32x4 cacc[4] = {};

    // ---------------- pass 2: attn write + context ----------------
    for (int kt = 0; kt < 32; ++kt) {
        const int k0 = kt * 64;
        __syncthreads();
        {
            const int row = t >> 2, c = (t & 3) * 16;
            const short8* srck = (const short8*)((const short*)kh + headbase + (size_t)(k0 + row) * DKV + c);
            *(short8*)&Ks[row][c]     = srck[0];
            *(short8*)&Ks[row][c + 8] = srck[1];
            const short8* srcv = (const short8*)((const short*)vh + headbase + (size_t)(k0 + row) * DKV + c);
            short8 v0 = srcv[0], v1 = srcv[1];
            #pragma unroll
            for (int i = 0; i < 8; i++) VsT[c + i][row] = v0[i];
            #pragma unroll
            for (int i = 0; i < 8; i++) VsT[c + 8 + i][row] = v1[i];
        }
        __syncthreads();
        #pragma unroll
        for (int fc = 0; fc < 4; ++fc) {
            short8 bk0 = *(const short8*)&Ks[fc * 16 + lr][kb];
            short8 bk1 = *(const short8*)&Ks[fc * 16 + lr][32 + kb];
            f32x4 sc = {0.f, 0.f, 0.f, 0.f};
            sc = MFMA16(aq0, bk0, sc);
            sc = MFMA16(aq1, bk1, sc);
            const int kcol = k0 + fc * 16 + lr;
            #pragma unroll
            for (int r = 0; r < 4; ++r) {
                const int qrow = q0 + w * 16 + rbase + r;
                const int mv = mask[((size_t)b * SS + qrow) * SS + kcol];
                float p = mv ? 0.f : __expf(sc[r] * 0.125f) * linv[r];
                attn[(((size_t)(b * HH + h)) * SS + qrow) * SS + kcol] = p;
                Ps[w * 16 + rbase + r][fc * 16 + lr] = f2bf(p);
            }
        }
        __syncthreads();
        short8 ap0 = *(const short8*)&Ps[w * 16 + lr][kb];
        short8 ap1 = *(const short8*)&Ps[w * 16 + lr][32 + kb];
        #pragma unroll
        for (int fd = 0; fd < 4; ++fd) {
            short8 bv0 = *(const short8*)&VsT[fd * 16 + lr][kb];
            short8 bv1 = *(const short8*)&VsT[fd * 16 + lr][32 + kb];
            cacc[fd] = MFMA16(ap0, bv0, cacc[fd]);
            cacc[fd] = MFMA16(ap1, bv1, cacc[fd]);
        }
    }

    // write context in [b][s][h*64+d] layout (bf16) for the output GEMM
    #pragma unroll
    for (int fd = 0; fd < 4; ++fd) {
        #pragma unroll
        for (int r = 0; r < 4; r++) {
            const int qrow = q0 + w * 16 + rbase + r;
            ctx[((size_t)b * SS + qrow) * DD + h * DKV + fd * 16 + lr] =
                __float2bfloat16(cacc[fd][r]);
        }
    }
}

// ---------------------------------------------------------------------------
// LayerNorm in place on out[4096][1024], biased var, eps=1e-5
// ---------------------------------------------------------------------------
__global__ __launch_bounds__(256) void ln_kernel(
    float* __restrict__ io, const float* __restrict__ g, const float* __restrict__ bta)
{
    const int row = blockIdx.x;
    const int t = threadIdx.x;
    float* p = io + (size_t)row * DD;
    float4 x = *(float4*)(p + t * 4);
    float s  = x.x + x.y + x.z + x.w;
    float s2 = x.x * x.x + x.y * x.y + x.z * x.z + x.w * x.w;
    #pragma unroll
    for (int off = 32; off; off >>= 1) {
        s  += __shfl_xor(s, off);
        s2 += __shfl_xor(s2, off);
    }
    __shared__ float as_[4], bs_[4];
    const int w = t >> 6, l = t & 63;
    if (!l) { as_[w] = s; bs_[w] = s2; }
    __syncthreads();
    s  = as_[0] + as_[1] + as_[2] + as_[3];
    s2 = bs_[0] + bs_[1] + bs_[2] + bs_[3];
    const float mu  = s * (1.f / DD);
    const float var = s2 * (1.f / DD) - mu * mu;
    const float rs  = rsqrtf(var + 1e-5f);
    float4 gv = *(const float4*)(g + t * 4);
    float4 bv = *(const float4*)(bta + t * 4);
    float4 o;
    o.x = (x.x - mu) * rs * gv.x + bv.x;
    o.y = (x.y - mu) * rs * gv.y + bv.y;
    o.z = (x.z - mu) * rs * gv.z + bv.z;
    o.w = (x.w - mu) * rs * gv.w + bv.w;
    *(float4*)(p + t * 4) = o;
}

// ---------------------------------------------------------------------------
extern "C" void kernel_launch(void* const* d_in, const int* in_sizes, int n_in,
                              void* d_out, int out_size, void* d_ws, size_t ws_size,
                              hipStream_t stream)
{
    (void)in_sizes; (void)n_in; (void)out_size; (void)ws_size;
    const float* q     = (const float*)d_in[0];
    const float* k     = (const float*)d_in[1];
    const float* v     = (const float*)d_in[2];
    const int*   mask  = (const int*)d_in[3];
    const float* wq    = (const float*)d_in[4];
    const float* bq    = (const float*)d_in[5];
    const float* wk    = (const float*)d_in[6];
    const float* bk    = (const float*)d_in[7];
    const float* wv    = (const float*)d_in[8];
    const float* bv    = (const float*)d_in[9];
    const float* wo    = (const float*)d_in[10];
    const float* bo    = (const float*)d_in[11];
    const float* gamma = (const float*)d_in[12];
    const float* beta  = (const float*)d_in[13];

    float* out  = (float*)d_out;                    // [B,S,D]
    float* attn = out + (size_t)BB * SS * DD;       // [B,H,S,S]

    const size_t hsz = (size_t)BB * HH * SS * DKV;  // 4,194,304
    __hip_bfloat16* qhp = (__hip_bfloat16*)d_ws;
    __hip_bfloat16* khp = qhp + hsz;
    __hip_bfloat16* vhp = khp + hsz;
    __hip_bfloat16* ctx = vhp + hsz;

    dim3 gg(32, 8);  // M/128 x N/128
    proj_kernel<<<gg, 256, 0, stream>>>(q, wq, bq, qhp);
    proj_kernel<<<gg, 256, 0, stream>>>(k, wk, bk, khp);
    proj_kernel<<<gg, 256, 0, stream>>>(v, wv, bv, vhp);
    attn_kernel<<<BB * HH * 32, 256, 0, stream>>>(qhp, khp, vhp, mask, attn, ctx);
    outproj_kernel<<<gg, 256, 0, stream>>>(ctx, wo, bo, q, out);
    ln_kernel<<<BB * SS, 256, 0, stream>>>(out, gamma, beta);
}